// Round 1
// baseline (64.385 us; speedup 1.0000x reference)
//
#include <hip/hip_runtime.h>
#include <hip/hip_bf16.h>

// Segment-sum over ragged contiguous segments.
// data: [TOTAL=1048576, D=64] fp32, lengths: [8192] int32 (sum == TOTAL)
// out:  [8192, 64] fp32
//
// Kernel 1: exclusive prefix sum of lengths -> offsets (d_ws)
// Kernel 2: one wave per segment; lane = rg*16 + c; thread sums float4
//           column-quad c over rows rg, rg+4, ...; shfl-reduce over rg.

__global__ void seg_scan_kernel(const int* __restrict__ lengths, int n_seg,
                                int* __restrict__ offsets) {
    __shared__ int partial[256];
    const int tid = threadIdx.x;
    const int chunk = (n_seg + 255) / 256;  // 32 for n_seg=8192
    const int base = tid * chunk;

    int sum = 0;
    for (int i = 0; i < chunk; ++i) {
        int idx = base + i;
        if (idx < n_seg) sum += lengths[idx];
    }
    partial[tid] = sum;
    __syncthreads();

    // Hillis-Steele inclusive scan over the 256 partials.
    for (int off = 1; off < 256; off <<= 1) {
        int v = (tid >= off) ? partial[tid - off] : 0;
        __syncthreads();
        partial[tid] += v;
        __syncthreads();
    }

    int run = (tid == 0) ? 0 : partial[tid - 1];  // exclusive
    for (int i = 0; i < chunk; ++i) {
        int idx = base + i;
        if (idx < n_seg) {
            offsets[idx] = run;
            run += lengths[idx];
        }
    }
}

__global__ __launch_bounds__(256) void seg_sum_kernel(
    const float* __restrict__ data, const int* __restrict__ lengths,
    const int* __restrict__ offsets, float* __restrict__ out, int n_seg) {
    const int wave = threadIdx.x >> 6;           // 0..3
    const int lane = threadIdx.x & 63;
    const int s = blockIdx.x * 4 + wave;
    if (s >= n_seg) return;

    const int start = offsets[s];
    const int len = lengths[s];

    const int c = lane & 15;    // float4 column quad: covers D=64 as 16 x float4
    const int rg = lane >> 4;   // row group 0..3

    const float4* __restrict__ base =
        reinterpret_cast<const float4*>(data) + (size_t)start * 16 + c;

    float4 acc = make_float4(0.f, 0.f, 0.f, 0.f);
    for (int r = rg; r < len; r += 4) {
        float4 v = base[(size_t)r * 16];
        acc.x += v.x; acc.y += v.y; acc.z += v.z; acc.w += v.w;
    }

    // Reduce across the 4 row groups (lanes with identical c differ by 16).
    #pragma unroll
    for (int off = 32; off >= 16; off >>= 1) {
        acc.x += __shfl_down(acc.x, off);
        acc.y += __shfl_down(acc.y, off);
        acc.z += __shfl_down(acc.z, off);
        acc.w += __shfl_down(acc.w, off);
    }

    if (rg == 0) {
        reinterpret_cast<float4*>(out)[(size_t)s * 16 + c] = acc;
    }
}

extern "C" void kernel_launch(void* const* d_in, const int* in_sizes, int n_in,
                              void* d_out, int out_size, void* d_ws, size_t ws_size,
                              hipStream_t stream) {
    const float* data = (const float*)d_in[0];
    const int* lengths = (const int*)d_in[1];
    const int n_seg = in_sizes[1];

    int* offsets = (int*)d_ws;       // n_seg ints (32 KB) of scratch
    float* out = (float*)d_out;

    seg_scan_kernel<<<1, 256, 0, stream>>>(lengths, n_seg, offsets);

    const int segs_per_block = 4;    // 4 waves of 64 per block
    const int grid = (n_seg + segs_per_block - 1) / segs_per_block;
    seg_sum_kernel<<<grid, 256, 0, stream>>>(data, lengths, offsets, out, n_seg);
}

// Round 2
// 47.947 us; speedup vs baseline: 1.3428x; 1.3428x over previous
//
#include <hip/hip_runtime.h>
#include <hip/hip_bf16.h>

// Segment-sum over ragged contiguous segments, single fused kernel.
// data: [TOTAL=1048576, D=64] fp32, lengths: [8192] int32 (sum == TOTAL)
// out:  [8192, 64] fp32
//
// One block = 4 waves = 4 consecutive segments. Each block redundantly
// computes prefix[4b] by block-reducing lengths[0..4b) (int4-vectorized;
// the 32 KB lengths array is L2-resident, so re-reads are cheap). Wave w
// then adds its <=3 intra-block predecessor lengths.
// Streaming loop: lane = rg*16 + c; thread sums float4 column-quad c over
// rows rg, rg+4, ...; unrolled x2 (8 independent accumulator chains);
// shfl-reduce across the 4 row groups; lanes 0..15 store one float4 each.

__global__ __launch_bounds__(256) void seg_sum_fused(
    const float* __restrict__ data, const int* __restrict__ lengths,
    float* __restrict__ out, int n_seg) {
    const int tid = threadIdx.x;
    const int wave = tid >> 6;   // 0..3
    const int lane = tid & 63;
    const int s0 = blockIdx.x * 4;

    // ---- block-wide sum of lengths[0..s0) ----
    const int n4 = s0 >> 2;  // s0 is a multiple of 4
    const int4* __restrict__ l4 = reinterpret_cast<const int4*>(lengths);
    int psum = 0;
    for (int i = tid; i < n4; i += 256) {
        int4 v = l4[i];
        psum += v.x + v.y + v.z + v.w;
    }
    #pragma unroll
    for (int off = 32; off >= 1; off >>= 1) psum += __shfl_down(psum, off);

    __shared__ int wsum[4];
    if (lane == 0) wsum[wave] = psum;
    __syncthreads();
    const int S = wsum[0] + wsum[1] + wsum[2] + wsum[3];  // prefix[s0]

    const int s = s0 + wave;
    if (s >= n_seg) return;

    int start = S;
    for (int j = 0; j < wave; ++j) start += lengths[s0 + j];
    const int len = lengths[s];

    // ---- streaming sum ----
    const int c = lane & 15;   // float4 column quad (16 x float4 = 64 floats)
    const int rg = lane >> 4;  // row group 0..3

    const float4* __restrict__ base =
        reinterpret_cast<const float4*>(data) + (size_t)start * 16 + c;

    float4 a0 = make_float4(0.f, 0.f, 0.f, 0.f);
    float4 a1 = make_float4(0.f, 0.f, 0.f, 0.f);

    int r = rg;
    for (; r + 4 < len; r += 8) {
        float4 v0 = base[(size_t)r * 16];
        float4 v1 = base[(size_t)(r + 4) * 16];
        a0.x += v0.x; a0.y += v0.y; a0.z += v0.z; a0.w += v0.w;
        a1.x += v1.x; a1.y += v1.y; a1.z += v1.z; a1.w += v1.w;
    }
    if (r < len) {
        float4 v0 = base[(size_t)r * 16];
        a0.x += v0.x; a0.y += v0.y; a0.z += v0.z; a0.w += v0.w;
    }
    a0.x += a1.x; a0.y += a1.y; a0.z += a1.z; a0.w += a1.w;

    // Reduce across the 4 row groups (same c, lane stride 16).
    #pragma unroll
    for (int off = 32; off >= 16; off >>= 1) {
        a0.x += __shfl_down(a0.x, off);
        a0.y += __shfl_down(a0.y, off);
        a0.z += __shfl_down(a0.z, off);
        a0.w += __shfl_down(a0.w, off);
    }

    if (rg == 0) {
        reinterpret_cast<float4*>(out)[(size_t)s * 16 + c] = a0;
    }
}

extern "C" void kernel_launch(void* const* d_in, const int* in_sizes, int n_in,
                              void* d_out, int out_size, void* d_ws, size_t ws_size,
                              hipStream_t stream) {
    const float* data = (const float*)d_in[0];
    const int* lengths = (const int*)d_in[1];
    const int n_seg = in_sizes[1];
    float* out = (float*)d_out;

    const int grid = (n_seg + 3) / 4;  // 4 segments (waves) per block
    seg_sum_fused<<<grid, 256, 0, stream>>>(data, lengths, out, n_seg);
}

// Round 3
// 46.494 us; speedup vs baseline: 1.3848x; 1.0313x over previous
//
#include <hip/hip_runtime.h>
#include <hip/hip_bf16.h>

// Segment-sum over ragged contiguous segments, single fused kernel.
// data: [TOTAL=1048576, D=64] fp32, lengths: [8192] int32 (sum == TOTAL)
// out:  [8192, 64] fp32
//
// One block = 8 waves (512 thr) = 8 consecutive segments. Each block
// redundantly computes prefix[8b] by block-reducing lengths[0..8b)
// (int4-vectorized, L2-resident; 1024 blocks -> ~16 MB aggregate L2
// traffic at t=0). The block's own 8 lengths are cached in LDS; wave w
// adds its <w predecessors. Streaming loop: lane = rg*16 + c; thread sums
// float4 column-quad c over rows rg, rg+4, ...; 4-deep unroll (4
// independent accumulator chains, 4 loads in flight, base+imm offsets);
// shfl-reduce across the 4 row groups; lanes 0..15 store one float4 each.

__global__ __launch_bounds__(512) void seg_sum_fused(
    const float* __restrict__ data, const int* __restrict__ lengths,
    float* __restrict__ out, int n_seg) {
    const int tid = threadIdx.x;
    const int wave = tid >> 6;   // 0..7
    const int lane = tid & 63;
    const int s0 = blockIdx.x * 8;

    __shared__ int wsum[8];
    __shared__ int slen[8];

    if (tid < 8) {
        int idx = s0 + tid;
        slen[tid] = (idx < n_seg) ? lengths[idx] : 0;
    }

    // ---- block-wide sum of lengths[0..s0) ----
    const int n4 = s0 >> 2;  // s0 is a multiple of 8 -> multiple of 4
    const int4* __restrict__ l4 = reinterpret_cast<const int4*>(lengths);
    int psum = 0;
    for (int i = tid; i < n4; i += 512) {
        int4 v = l4[i];
        psum += v.x + v.y + v.z + v.w;
    }
    #pragma unroll
    for (int off = 32; off >= 1; off >>= 1) psum += __shfl_down(psum, off);
    if (lane == 0) wsum[wave] = psum;
    __syncthreads();

    int S = 0;
    #pragma unroll
    for (int j = 0; j < 8; ++j) S += wsum[j];  // prefix[s0]

    const int s = s0 + wave;
    if (s >= n_seg) return;

    int start = S;
    for (int j = 0; j < wave; ++j) start += slen[j];
    const int len = slen[wave];

    // ---- streaming sum ----
    const int c = lane & 15;   // float4 column quad (16 x float4 = 64 floats)
    const int rg = lane >> 4;  // row group 0..3

    const float4* __restrict__ p =
        reinterpret_cast<const float4*>(data) + (size_t)(start + rg) * 16 + c;

    float4 a0 = make_float4(0.f, 0.f, 0.f, 0.f);
    float4 a1 = make_float4(0.f, 0.f, 0.f, 0.f);
    float4 a2 = make_float4(0.f, 0.f, 0.f, 0.f);
    float4 a3 = make_float4(0.f, 0.f, 0.f, 0.f);

    int r = rg;
    for (; r + 12 < len; r += 16, p += 256) {
        float4 v0 = p[0];
        float4 v1 = p[64];
        float4 v2 = p[128];
        float4 v3 = p[192];
        a0.x += v0.x; a0.y += v0.y; a0.z += v0.z; a0.w += v0.w;
        a1.x += v1.x; a1.y += v1.y; a1.z += v1.z; a1.w += v1.w;
        a2.x += v2.x; a2.y += v2.y; a2.z += v2.z; a2.w += v2.w;
        a3.x += v3.x; a3.y += v3.y; a3.z += v3.z; a3.w += v3.w;
    }
    for (; r < len; r += 4, p += 64) {
        float4 v0 = p[0];
        a0.x += v0.x; a0.y += v0.y; a0.z += v0.z; a0.w += v0.w;
    }
    a0.x += a1.x + a2.x + a3.x;
    a0.y += a1.y + a2.y + a3.y;
    a0.z += a1.z + a2.z + a3.z;
    a0.w += a1.w + a2.w + a3.w;

    // Reduce across the 4 row groups (same c, lane stride 16).
    #pragma unroll
    for (int off = 32; off >= 16; off >>= 1) {
        a0.x += __shfl_down(a0.x, off);
        a0.y += __shfl_down(a0.y, off);
        a0.z += __shfl_down(a0.z, off);
        a0.w += __shfl_down(a0.w, off);
    }

    if (rg == 0) {
        reinterpret_cast<float4*>(out)[(size_t)s * 16 + c] = a0;
    }
}

extern "C" void kernel_launch(void* const* d_in, const int* in_sizes, int n_in,
                              void* d_out, int out_size, void* d_ws, size_t ws_size,
                              hipStream_t stream) {
    const float* data = (const float*)d_in[0];
    const int* lengths = (const int*)d_in[1];
    const int n_seg = in_sizes[1];
    float* out = (float*)d_out;

    const int grid = (n_seg + 7) / 8;  // 8 segments (waves) per block
    seg_sum_fused<<<grid, 512, 0, stream>>>(data, lengths, out, n_seg);
}